// Round 8
// baseline (2487.485 us; speedup 1.0000x reference)
//
#include <hip/hip_runtime.h>
#include <hip/hip_bf16.h>

#define TSTEPS 512
#define BATCH  64
#define DIM    512
#define NWG    8

using short8 = __attribute__((ext_vector_type(8))) short;
using f32x4  = __attribute__((ext_vector_type(4))) float;

__device__ __forceinline__ unsigned short f2bf(float f) {
    unsigned u = __builtin_bit_cast(unsigned, f);
    unsigned r = (u + 0x7FFFu + ((u >> 16) & 1u)) >> 16;   // RNE
    return (unsigned short)r;
}

// ---------- fp32 [a][b] -> bf16 [b][a]  (for xh and o) ----------
__global__ void conv_T(const float* __restrict__ src, unsigned short* __restrict__ dst) {
    __shared__ float tile[32][33];
    const int bx = blockIdx.x * 32, by = blockIdx.y * 32;
    const int tx = threadIdx.x & 31, ty = threadIdx.x >> 5;
#pragma unroll
    for (int k = 0; k < 32; k += 8)
        tile[ty + k][tx] = src[(size_t)(by + ty + k) * DIM + bx + tx];
    __syncthreads();
#pragma unroll
    for (int k = 0; k < 32; k += 8)
        dst[(size_t)(bx + ty + k) * DIM + by + tx] = f2bf(tile[tx][ty + k]);
}

// ---------- XW = x @ xh + hb (bf16 MFMA) -> d_out, remapped [t][kg][m][col] float4(r) ----------
__global__ __launch_bounds__(256) void gemm_xwm(
    const float* __restrict__ X,            // [32768][512] fp32
    const unsigned short* __restrict__ Bt,  // xhT bf16 [col][k]
    const float* __restrict__ bias, float* __restrict__ Out)
{
    __shared__ unsigned short As[128 * 40];
    __shared__ unsigned short Bs[128 * 40];
    const int tid = threadIdx.x;
    const int m0 = blockIdx.x * 128, n0 = blockIdx.y * 128;
    const int lane = tid & 63, wv = tid >> 6;
    const int ln15 = lane & 15, kg = lane >> 4;
    const int wr = (wv >> 1) * 64, wc = (wv & 1) * 64;

    f32x4 acc[4][4];
#pragma unroll
    for (int m = 0; m < 4; ++m)
#pragma unroll
        for (int n = 0; n < 4; ++n) acc[m][n] = f32x4{0.f, 0.f, 0.f, 0.f};

    const int arow = tid >> 1, ahalf = tid & 1;      // 2 threads/row, 16 elements each
    for (int k0 = 0; k0 < DIM; k0 += 32) {
        const float4* ga = reinterpret_cast<const float4*>(
            X + (size_t)(m0 + arow) * DIM + k0 + ahalf * 16);
        float4 a0 = ga[0], a1 = ga[1], a2 = ga[2], a3 = ga[3];
        const ulonglong2* gb = reinterpret_cast<const ulonglong2*>(
            Bt + (size_t)(n0 + arow) * DIM + k0 + ahalf * 16);
        ulonglong2 bv0 = gb[0], bv1 = gb[1];
        __syncthreads();
        {
            unsigned long long p[4];
            const float4 av[4] = {a0, a1, a2, a3};
#pragma unroll
            for (int q = 0; q < 4; ++q)
                p[q] = (unsigned long long)f2bf(av[q].x)
                     | ((unsigned long long)f2bf(av[q].y) << 16)
                     | ((unsigned long long)f2bf(av[q].z) << 32)
                     | ((unsigned long long)f2bf(av[q].w) << 48);
            unsigned long long* s = reinterpret_cast<unsigned long long*>(&As[arow * 40 + ahalf * 16]);
            s[0] = p[0]; s[1] = p[1]; s[2] = p[2]; s[3] = p[3];
            *reinterpret_cast<ulonglong2*>(&Bs[arow * 40 + ahalf * 16]) = bv0;
            *reinterpret_cast<ulonglong2*>(&Bs[arow * 40 + ahalf * 16 + 8]) = bv1;
        }
        __syncthreads();
        short8 af[4], bf[4];
#pragma unroll
        for (int m = 0; m < 4; ++m)
            af[m] = *reinterpret_cast<const short8*>(&As[(wr + m * 16 + ln15) * 40 + kg * 8]);
#pragma unroll
        for (int n = 0; n < 4; ++n)
            bf[n] = *reinterpret_cast<const short8*>(&Bs[(wc + n * 16 + ln15) * 40 + kg * 8]);
#pragma unroll
        for (int m = 0; m < 4; ++m)
#pragma unroll
            for (int n = 0; n < 4; ++n)
                acc[m][n] = __builtin_amdgcn_mfma_f32_16x16x32_bf16(af[m], bf[n], acc[m][n], 0, 0, 0);
    }
    float4* Out4 = reinterpret_cast<float4*>(Out);
#pragma unroll
    for (int n = 0; n < 4; ++n) {
        int col = n0 + wc + n * 16 + ln15;
        float bb = bias[col];
#pragma unroll
        for (int m = 0; m < 4; ++m) {
            int t = (m0 + wr) >> 6;
            float4 v;
            v.x = acc[m][n][0] + bb; v.y = acc[m][n][1] + bb;
            v.z = acc[m][n][2] + bb; v.w = acc[m][n][3] + bb;
            Out4[(((size_t)t * 4 + kg) * 4 + m) * DIM + col] = v;
        }
    }
}

// ---------- persistent scan: tagged-data protocol (no fences, no flags, no barrier) ----------
// tbuf: 3 slots x [64 rows][256 colpairs] u64, u64 = bf16(col even) | bf16(col odd)<<16 | tag<<32.
// Step t reads slot t%3 expecting tag t+1; writes slot (t+1)%3 with tag t+2 (atomic relaxed
// agent u64s: single-copy atomic => tag validates data; visibility is autonomous).
// hist gets the bf16 H history via plain stores for gemm_y (visible at kernel end).
__global__ __launch_bounds__(256, 1) void rnn_scan(
    const float* __restrict__ hh, const float* __restrict__ xwb,
    const float* __restrict__ h0, unsigned long long* __restrict__ tbuf,
    unsigned short* __restrict__ hist)
{
    const int tid  = threadIdx.x;
    const int wg   = blockIdx.x;
    const int lane = tid & 63;
    const int wv   = __builtin_amdgcn_readfirstlane(tid >> 6);
    const int ln15 = lane & 15, kg = lane >> 4;
    const int colw = wg * 64 + wv * 16 + ln15;

    __shared__ unsigned long long hsU[2 * 8192];   // 2 x 64KB bf16 H tile (double buffer)

    // hh columns -> B-fragments, once
    short8 Bhh[16];
#pragma unroll
    for (int kk = 0; kk < 16; ++kk) {
        short8 bh;
#pragma unroll
        for (int j = 0; j < 8; ++j) {
            int k = kk * 32 + kg * 8 + j;
            bh[j] = (short)f2bf(hh[(size_t)k * DIM + colw]);
        }
        Bhh[kk] = bh;
    }

    // prefill slot 0 (tag 1): this WG's 32 colpairs x 64 rows, h0 broadcast over batch
    {
        int colp = wg * 32 + (tid & 31);
        unsigned pair = (unsigned)f2bf(h0[2 * colp]) | ((unsigned)f2bf(h0[2 * colp + 1]) << 16);
        unsigned long long v = (unsigned long long)pair | (1ull << 32);
#pragma unroll
        for (int q = 0; q < 8; ++q) {
            int row = (tid >> 5) * 8 + q;
            __hip_atomic_store(&tbuf[row * 256 + colp], v,
                               __ATOMIC_RELAXED, __HIP_MEMORY_SCOPE_AGENT);
        }
    }

    const float4* xw4 = reinterpret_cast<const float4*>(xwb);

    for (int t = 0; t < TSTEPS; ++t) {
        // ---- XW loads first (latency overlaps the poll) ----
        f32x4 xwr[4];
#pragma unroll
        for (int m = 0; m < 4; ++m) {
            float4 v = xw4[(((size_t)t * 4 + kg) * 4 + m) * DIM + colw];
            xwr[m] = f32x4{v.x, v.y, v.z, v.w};
        }

        // ---- stage slot t%3 -> LDS buf t&1, two 32-row batches ----
        const unsigned long long* src = tbuf + (size_t)(t % 3) * 16384 + tid;
        const unsigned expect = (unsigned)(t + 1);
        char* lbase = reinterpret_cast<char*>(hsU) + (t & 1) * 65536;
#pragma unroll 1
        for (int half = 0; half < 2; ++half) {
            unsigned long long va[32];
            for (;;) {
#pragma unroll
                for (int a = 0; a < 32; ++a)
                    va[a] = __hip_atomic_load(src + (half * 32 + a) * 256,
                                              __ATOMIC_RELAXED, __HIP_MEMORY_SCOPE_AGENT);
                unsigned acc = 0;
#pragma unroll
                for (int a = 0; a < 32; ++a)
                    acc |= ((unsigned)(va[a] >> 32)) ^ expect;
                if (!__any((acc & 0xffffu) != 0)) break;   // all words fresh
                __builtin_amdgcn_s_sleep(1);
            }
#pragma unroll
            for (int a = 0; a < 32; ++a) {
                int row = half * 32 + a;
                int byte = ((row << 10) + (tid << 2)) ^ ((row & 7) << 4);
                *reinterpret_cast<unsigned*>(lbase + byte) = (unsigned)va[a];
            }
        }
        __syncthreads();   // LDS tile complete (also separates from prior-step MFMA reads)

        // ---- MFMA: acc_h = H_t @ hh ----
        f32x4 acch[4];
#pragma unroll
        for (int m = 0; m < 4; ++m) acch[m] = f32x4{0.f, 0.f, 0.f, 0.f};
#pragma unroll
        for (int kk = 0; kk < 16; ++kk) {
#pragma unroll
            for (int m = 0; m < 4; ++m) {
                int row = m * 16 + ln15;
                int byte = ((row << 10) + (kk << 6) + (kg << 4)) ^ ((row & 7) << 4);
                short8 a = *reinterpret_cast<const short8*>(lbase + byte);
                acch[m] = __builtin_amdgcn_mfma_f32_16x16x32_bf16(a, Bhh[kk], acch[m], 0, 0, 0);
            }
        }

        // ---- H_{t+1} = relu(XW_t + acc): hist (plain) + tagged col-pair u64s (atomic) ----
        const unsigned long long tagbits = ((unsigned long long)(t + 2)) << 32;
        unsigned long long* tdst = tbuf + (size_t)((t + 1) % 3) * 16384;
        unsigned short* hdst = hist + (size_t)(t + 1) * (BATCH * DIM);
        const bool evenlane = (ln15 & 1) == 0;
        const int colp = colw >> 1;
#pragma unroll
        for (int m = 0; m < 4; ++m)
#pragma unroll
            for (int r = 0; r < 4; ++r) {
                int row = m * 16 + kg * 4 + r;
                float hn = xwr[m][r] + acch[m][r];
                hn = hn > 0.f ? hn : 0.f;
                unsigned self = f2bf(hn);
                hdst[(size_t)row * DIM + colw] = (unsigned short)self;
                unsigned partner = (unsigned)__shfl_xor((int)self, 1);
                unsigned pair = evenlane ? (self | (partner << 16))
                                         : (partner | (self << 16));
                if (evenlane == (m < 2))   // even lanes publish m 0-1, odd lanes m 2-3
                    __hip_atomic_store(&tdst[row * 256 + colp], tagbits | (unsigned long long)pair,
                                       __ATOMIC_RELAXED, __HIP_MEMORY_SCOPE_AGENT);
            }
    }
}

// ---------- Y = Hist(slots 1..512) @ o : MFMA GEMM, 128x128x32 tiles ----------
__global__ __launch_bounds__(256) void gemm_y(
    const unsigned short* __restrict__ A,   // hist + 32768: [32768][512] bf16
    const unsigned short* __restrict__ Bt,  // oT bf16 [col][k]
    float* __restrict__ Out)                // [32768][512] fp32
{
    __shared__ unsigned short As[128 * 40];
    __shared__ unsigned short Bs[128 * 40];
    const int tid = threadIdx.x;
    const int m0 = blockIdx.x * 128, n0 = blockIdx.y * 128;
    const int lane = tid & 63, wv = tid >> 6;
    const int ln15 = lane & 15, kg = lane >> 4;
    const int wr = (wv >> 1) * 64, wc = (wv & 1) * 64;

    f32x4 acc[4][4];
#pragma unroll
    for (int m = 0; m < 4; ++m)
#pragma unroll
        for (int n = 0; n < 4; ++n) acc[m][n] = f32x4{0.f, 0.f, 0.f, 0.f};

    const int sr = tid & 127;
    for (int k0 = 0; k0 < DIM; k0 += 32) {
        const unsigned short* g = (tid < 128)
            ? A  + (size_t)(m0 + sr) * DIM + k0
            : Bt + (size_t)(n0 + sr) * DIM + k0;
        unsigned short* s = (tid < 128) ? &As[sr * 40] : &Bs[sr * 40];
        ulonglong2 v0 = reinterpret_cast<const ulonglong2*>(g)[0];
        ulonglong2 v1 = reinterpret_cast<const ulonglong2*>(g)[1];
        ulonglong2 v2 = reinterpret_cast<const ulonglong2*>(g)[2];
        ulonglong2 v3 = reinterpret_cast<const ulonglong2*>(g)[3];
        __syncthreads();
        reinterpret_cast<ulonglong2*>(s)[0] = v0;
        reinterpret_cast<ulonglong2*>(s)[1] = v1;
        reinterpret_cast<ulonglong2*>(s)[2] = v2;
        reinterpret_cast<ulonglong2*>(s)[3] = v3;
        __syncthreads();
        short8 af[4], bf[4];
#pragma unroll
        for (int m = 0; m < 4; ++m)
            af[m] = *reinterpret_cast<const short8*>(&As[(wr + m * 16 + ln15) * 40 + kg * 8]);
#pragma unroll
        for (int n = 0; n < 4; ++n)
            bf[n] = *reinterpret_cast<const short8*>(&Bs[(wc + n * 16 + ln15) * 40 + kg * 8]);
#pragma unroll
        for (int m = 0; m < 4; ++m)
#pragma unroll
            for (int n = 0; n < 4; ++n)
                acc[m][n] = __builtin_amdgcn_mfma_f32_16x16x32_bf16(af[m], bf[n], acc[m][n], 0, 0, 0);
    }
#pragma unroll
    for (int m = 0; m < 4; ++m)
#pragma unroll
        for (int n = 0; n < 4; ++n)
#pragma unroll
            for (int r = 0; r < 4; ++r) {
                int row = m0 + wr + m * 16 + kg * 4 + r;
                int col = n0 + wc + n * 16 + ln15;
                Out[(size_t)row * DIM + col] = acc[m][n][r];
            }
}

extern "C" void kernel_launch(void* const* d_in, const int* in_sizes, int n_in,
                              void* d_out, int out_size, void* d_ws, size_t ws_size,
                              hipStream_t stream) {
    const float* x  = (const float*)d_in[0];
    const float* xh = (const float*)d_in[1];
    const float* hh = (const float*)d_in[2];
    const float* hb = (const float*)d_in[3];
    const float* o  = (const float*)d_in[4];
    const float* h0 = (const float*)d_in[5];
    float* out = (float*)d_out;

    unsigned long long* tbuf = (unsigned long long*)d_ws;               // 3*16384*8 = 384KB
    unsigned short* hist = (unsigned short*)((char*)d_ws + 393216);     // 513 * 64KB
    unsigned short* oT  = (unsigned short*)((char*)d_ws + 393216 + (size_t)513 * 65536);
    unsigned short* xhT = oT + (size_t)DIM * DIM;

    (void)hipMemsetAsync(d_ws, 0, 393216, stream);   // clear tags (first-call garbage)
    conv_T<<<dim3(16, 16), 256, 0, stream>>>(o, oT);
    conv_T<<<dim3(16, 16), 256, 0, stream>>>(xh, xhT);
    gemm_xwm<<<dim3(256, 4), 256, 0, stream>>>(x, xhT, hb, out);   // out <- XWB (remapped)
    rnn_scan<<<NWG, 256, 0, stream>>>(hh, out, h0, tbuf, hist);
    gemm_y<<<dim3(256, 4), 256, 0, stream>>>(hist + 32768, oT, out);  // out <- Y
}